// Round 4
// baseline (244.031 us; speedup 1.0000x reference)
//
#include <hip/hip_runtime.h>
#include <hip/hip_bf16.h>
#include <cmath>

// Problem constants
#define BATCH 8
#define NH 8
#define BH 64          // BATCH*NH
#define SEQ 1024
#define DH 64          // head dim
#define NM 64          // modes

// ws layout (floats):
//  P   : [inp 2][tq 4][bh 64][c 2][m 64][d 64] = 4,194,304
//  C1c : [bh 64][i 64][q 64][c 2]              =   524,288
//  C2s : [bh 64][m 64][j 64][c 2]              =   524,288  (scaled, m-major)
//  T   : [t 1024][re 64 | im 64]               =   131,072  (fwd twiddle table)
// total 5,373,952 floats = 21.5 MB
#define P_PLANE 4096   // 64m*64d
#define P_FLOATS (2*4*64*2*4096)
#define C1C_OFF  P_FLOATS
#define C2_OFF   (C1C_OFF + 64*64*64*2)
#define T_OFF    (C2_OFF + 64*64*64*2)

// ---------------------------------------------------------------------------
// Kernel 0: forward twiddle table. T[t][m] = e^{-2pi i m t / 1024}, exact per
// entry (no rotator drift). 256 blocks x 256 thr.
// ---------------------------------------------------------------------------
__global__ __launch_bounds__(256) void k_twid(float* __restrict__ T) {
  const int idx = blockIdx.x * 256 + threadIdx.x;  // t*64 + m, 65536 total
  const int t = idx >> 6, m = idx & 63;
  const int p = (t * m) & 1023;
  const float ph = (float)p * (1.0f / 512.0f);
  T[(size_t)t * 128 + m]      = cospif(ph);
  T[(size_t)t * 128 + 64 + m] = -sinpif(ph);
}

// ---------------------------------------------------------------------------
// Kernel 1: forward partial DFT, LDS-free. grid = (bh 64, inp 2, tq 4) = 512
// blocks x 256 thr. lane = d (coalesced x loads + P stores); wave owns 16
// modes; twiddles arrive via wave-uniform SCALAR loads from T (SMEM pipe,
// no VALU, no LDS port, no barriers). Inner loop = 32 v_fmac per t.
// ---------------------------------------------------------------------------
__global__ __launch_bounds__(256) void k_dft(const float* __restrict__ q,
                                             const float* __restrict__ k,
                                             const float* __restrict__ T,
                                             float* __restrict__ P) {
  const int bid = blockIdx.x;
  const int bh = bid & 63;
  const int inp = (bid >> 6) & 1;
  const int tq = bid >> 7;  // 0..3, 256 samples each
  const float* x = (inp ? k : q) + (size_t)bh * (SEQ * DH);  // [t][d]

  const int tid = threadIdx.x;
  const int lane = tid & 63;                                  // d
  const int wv = __builtin_amdgcn_readfirstlane(tid >> 6);    // wave id (sgpr)
  const int m0 = wv * 16;

  float ar[16] = {0.f}, ai[16] = {0.f};
  const int tbase = tq * 256;
  const float* xp = x + (size_t)tbase * DH + lane;
  const float* Tb = T + (size_t)tbase * 128 + m0;

#pragma unroll 4
  for (int t = 0; t < 256; ++t) {
    const float xv = xp[(size_t)t * DH];
    const float4* Tre = reinterpret_cast<const float4*>(Tb + (size_t)t * 128);
    const float4* Tim = reinterpret_cast<const float4*>(Tb + (size_t)t * 128 + 64);
    const float4 r0 = Tre[0], r1 = Tre[1], r2 = Tre[2], r3 = Tre[3];
    const float4 i0 = Tim[0], i1 = Tim[1], i2 = Tim[2], i3 = Tim[3];
    ar[0]  = fmaf(r0.x, xv, ar[0]);  ai[0]  = fmaf(i0.x, xv, ai[0]);
    ar[1]  = fmaf(r0.y, xv, ar[1]);  ai[1]  = fmaf(i0.y, xv, ai[1]);
    ar[2]  = fmaf(r0.z, xv, ar[2]);  ai[2]  = fmaf(i0.z, xv, ai[2]);
    ar[3]  = fmaf(r0.w, xv, ar[3]);  ai[3]  = fmaf(i0.w, xv, ai[3]);
    ar[4]  = fmaf(r1.x, xv, ar[4]);  ai[4]  = fmaf(i1.x, xv, ai[4]);
    ar[5]  = fmaf(r1.y, xv, ar[5]);  ai[5]  = fmaf(i1.y, xv, ai[5]);
    ar[6]  = fmaf(r1.z, xv, ar[6]);  ai[6]  = fmaf(i1.z, xv, ai[6]);
    ar[7]  = fmaf(r1.w, xv, ar[7]);  ai[7]  = fmaf(i1.w, xv, ai[7]);
    ar[8]  = fmaf(r2.x, xv, ar[8]);  ai[8]  = fmaf(i2.x, xv, ai[8]);
    ar[9]  = fmaf(r2.y, xv, ar[9]);  ai[9]  = fmaf(i2.y, xv, ai[9]);
    ar[10] = fmaf(r2.z, xv, ar[10]); ai[10] = fmaf(i2.z, xv, ai[10]);
    ar[11] = fmaf(r2.w, xv, ar[11]); ai[11] = fmaf(i2.w, xv, ai[11]);
    ar[12] = fmaf(r3.x, xv, ar[12]); ai[12] = fmaf(i3.x, xv, ai[12]);
    ar[13] = fmaf(r3.y, xv, ar[13]); ai[13] = fmaf(i3.y, xv, ai[13]);
    ar[14] = fmaf(r3.z, xv, ar[14]); ai[14] = fmaf(i3.z, xv, ai[14]);
    ar[15] = fmaf(r3.w, xv, ar[15]); ai[15] = fmaf(i3.w, xv, ai[15]);
  }

  // P[inp][tq][bh][c][m][d=lane]; coalesced 256B stores
  const size_t base = (((size_t)inp * 4 + tq) * 64 + bh) * 2 * P_PLANE;
#pragma unroll
  for (int mi = 0; mi < 16; ++mi) {
    P[base + (size_t)(m0 + mi) * 64 + lane]           = ar[mi];
    P[base + P_PLANE + (size_t)(m0 + mi) * 64 + lane] = ai[mi];
  }
}

// stable complex tanh: tanh(x+iy) = (sinh2x + i sin2y)/(cosh2x + cos2y)
__device__ __forceinline__ void ctanh_f(float x, float y, float& rr, float& ri) {
  float a = 2.0f * x, b = 2.0f * y;
  if (fabsf(a) > 20.0f) {
    rr = (a > 0.0f) ? 1.0f : -1.0f;
    ri = 0.0f;
  } else {
    float ea = expf(a), ena = expf(-a);
    float sb, cb;
    sincosf(b, &sb, &cb);
    float den = 0.5f * (ea + ena) + cb;
    rr = 0.5f * (ea - ena) / den;
    ri = sb / den;
  }
}

// ---------------------------------------------------------------------------
// Kernel 2a: scores -> ctanh -> context -> C1. grid = (bh, q-quarter) = 256
// blocks x 512 thr (8 waves/CU, doubled latency cover vs round 3).
// ---------------------------------------------------------------------------
__global__ __launch_bounds__(512) void k_mid_a(const float* __restrict__ P,
                                               float* __restrict__ C1c) {
  __shared__ float Kr[64][68], Ki[64][68];
  __shared__ float Qr[16][68], Qi[16][68];
  __shared__ float Ar[16][68], Ai[16][68];
  __shared__ float C1rs[64][17], C1is[64][17];

  const int tid = threadIdx.x;
  const int bh = blockIdx.x >> 2;
  const int qq = blockIdx.x & 3;

  // P[inp][tq][bh][c][m][d]
  size_t pq[4], pk[4];
#pragma unroll
  for (int t = 0; t < 4; ++t) {
    pq[t] = (((size_t)(0 * 4 + t) * 64 + bh) * 2) * P_PLANE;
    pk[t] = (((size_t)(1 * 4 + t) * 64 + bh) * 2) * P_PLANE;
  }

  for (int idx = tid; idx < 4096; idx += 512) {
    int kk = idx >> 6, dd = idx & 63;
    float r = 0.f, im = 0.f;
#pragma unroll
    for (int t = 0; t < 4; ++t) {
      r += P[pk[t] + idx];
      im += P[pk[t] + P_PLANE + idx];
    }
    Kr[kk][dd] = r; Ki[kk][dd] = im;
  }
  for (int idx = tid; idx < 1024; idx += 512) {
    int qi2 = idx >> 6, dd = idx & 63;
    int mm = qq * 16 + qi2;
    float r = 0.f, im = 0.f;
#pragma unroll
    for (int t = 0; t < 4; ++t) {
      r += P[pq[t] + mm * 64 + dd];
      im += P[pq[t] + P_PLANE + mm * 64 + dd];
    }
    Qr[qi2][dd] = r; Qi[qi2][dd] = im;
  }
  __syncthreads();

  // scores S[q][k] = sum_d Q[q][d]*K[k][d] (complex, no conj) -> ctanh
  {
    const int q = tid >> 5, k0 = tid & 31;
    float sr[2] = {0.f}, si[2] = {0.f};
    for (int d = 0; d < 64; d += 4) {
      const float4 qr = *reinterpret_cast<const float4*>(&Qr[q][d]);
      const float4 qi = *reinterpret_cast<const float4*>(&Qi[q][d]);
#pragma unroll
      for (int j = 0; j < 2; ++j) {
        const int kk = k0 + 32 * j;
        const float4 kr = *reinterpret_cast<const float4*>(&Kr[kk][d]);
        const float4 ki = *reinterpret_cast<const float4*>(&Ki[kk][d]);
        float s0 = sr[j], s1 = si[j];
        s0 = fmaf(qr.x, kr.x, s0); s0 = fmaf(-qi.x, ki.x, s0);
        s1 = fmaf(qr.x, ki.x, s1); s1 = fmaf(qi.x, kr.x, s1);
        s0 = fmaf(qr.y, kr.y, s0); s0 = fmaf(-qi.y, ki.y, s0);
        s1 = fmaf(qr.y, ki.y, s1); s1 = fmaf(qi.y, kr.y, s1);
        s0 = fmaf(qr.z, kr.z, s0); s0 = fmaf(-qi.z, ki.z, s0);
        s1 = fmaf(qr.z, ki.z, s1); s1 = fmaf(qi.z, kr.z, s1);
        s0 = fmaf(qr.w, kr.w, s0); s0 = fmaf(-qi.w, ki.w, s0);
        s1 = fmaf(qr.w, ki.w, s1); s1 = fmaf(qi.w, kr.w, s1);
        sr[j] = s0; si[j] = s1;
      }
    }
#pragma unroll
    for (int j = 0; j < 2; ++j) {
      float rr, ri;
      ctanh_f(sr[j], si[j], rr, ri);
      Ar[q][k0 + 32 * j] = rr;
      Ai[q][k0 + 32 * j] = ri;
    }
  }
  __syncthreads();

  // C1[d][q] = sum_k A[q][k]*K[k][d]
  {
    const int q = tid >> 5, d0 = (tid & 31) * 2;
    float cr[2] = {0.f}, ci[2] = {0.f};
    for (int kk = 0; kk < 64; ++kk) {
      float a_r = Ar[q][kk], a_i = Ai[q][kk];
      const float2 kr = *reinterpret_cast<const float2*>(&Kr[kk][d0]);
      const float2 ki = *reinterpret_cast<const float2*>(&Ki[kk][d0]);
      cr[0] = fmaf(a_r, kr.x, cr[0]); cr[0] = fmaf(-a_i, ki.x, cr[0]);
      ci[0] = fmaf(a_r, ki.x, ci[0]); ci[0] = fmaf(a_i, kr.x, ci[0]);
      cr[1] = fmaf(a_r, kr.y, cr[1]); cr[1] = fmaf(-a_i, ki.y, cr[1]);
      ci[1] = fmaf(a_r, ki.y, ci[1]); ci[1] = fmaf(a_i, kr.y, ci[1]);
    }
    C1rs[d0][q] = cr[0];     C1is[d0][q] = ci[0];
    C1rs[d0 + 1][q] = cr[1]; C1is[d0 + 1][q] = ci[1];
  }
  __syncthreads();

  // write C1c[bh][i][qglobal][2], interleaved complex, coalesced
  for (int idx = tid; idx < 1024; idx += 512) {
    int i = idx >> 4, ql = idx & 15;
    size_t o = (((size_t)bh * 64 + i) * 64 + qq * 16 + ql) * 2;
    *reinterpret_cast<float2*>(&C1c[o]) = make_float2(C1rs[i][ql], C1is[i][ql]);
  }
}

// ---------------------------------------------------------------------------
// Kernel 2b: C2s[b,h,m,j] = scale(m) * sum_i C1[b,h,i,m] * w[h,i,j,m]
// lane = m (q-mode) -> w and C1 loads coalesced. Output in m-major layout
// with irfft scale folded in (s for m=0, 2s Hermitian factor for m>0) so
// k_idft's scalar m-loop is uniform and its rotator stays unit-magnitude.
// grid = (h 8, j 64, b-quarter 4) = 2048 one-wave blocks = 8 waves/CU.
// ---------------------------------------------------------------------------
__global__ __launch_bounds__(64) void k_mid_b(const float* __restrict__ C1c,
                                              const float* __restrict__ wre,
                                              const float* __restrict__ wim,
                                              float* __restrict__ C2s) {
  const int bid = blockIdx.x;
  const int j = bid & 63;
  const int h = (bid >> 6) & 7;
  const int bq = bid >> 9;
  const int lane = threadIdx.x;  // q-mode

  const int bh0 = (bq * 2 + 0) * 8 + h;
  const int bh1 = (bq * 2 + 1) * 8 + h;
  const float2* c1a = reinterpret_cast<const float2*>(C1c) + (size_t)bh0 * 4096 + lane;
  const float2* c1b = reinterpret_cast<const float2*>(C1c) + (size_t)bh1 * 4096 + lane;
  const float* wrp = wre + ((size_t)h * 4096 + j) * 64 + lane;
  const float* wip = wim + ((size_t)h * 4096 + j) * 64 + lane;

  float ar0 = 0.f, ai0 = 0.f, ar1 = 0.f, ai1 = 0.f;
#pragma unroll 8
  for (int i = 0; i < 64; ++i) {
    float wr = wrp[(size_t)i * 4096];
    float wi = wip[(size_t)i * 4096];
    float2 ca = c1a[(size_t)i * 64];
    float2 cb = c1b[(size_t)i * 64];
    ar0 = fmaf(ca.x, wr, ar0); ar0 = fmaf(-ca.y, wi, ar0);
    ai0 = fmaf(ca.x, wi, ai0); ai0 = fmaf(ca.y, wr, ai0);
    ar1 = fmaf(cb.x, wr, ar1); ar1 = fmaf(-cb.y, wi, ar1);
    ai1 = fmaf(cb.x, wi, ai1); ai1 = fmaf(cb.y, wr, ai1);
  }
  const float s = 1.0f / (512.0f * 512.0f * 1024.0f);
  const float f = (lane == 0) ? s : 2.0f * s;
  // C2s[bh][m=lane][j][c]
  *reinterpret_cast<float2*>(&C2s[(((size_t)bh0 * 64 + lane) * 64 + j) * 2]) =
      make_float2(f * ar0, f * ai0);
  *reinterpret_cast<float2*>(&C2s[(((size_t)bh1 * 64 + lane) * 64 + j) * 2]) =
      make_float2(f * ar1, f * ai1);
}

// ---------------------------------------------------------------------------
// Kernel 3: inverse partial DFT, LDS-free. grid = (bh 64, tc 16, jh 2) = 2048
// blocks x 256 thr = 32 waves/CU. lane = t (coalesced out stores); per-thread
// 8 j's; C[m][j-tile] is wave-uniform -> scalar dwordx16 per m; per-lane
// unit rotator over m (63 steps, drift ~1e-5 relative, negligible post-tanh).
// out[t][j] = sum_m Re(C2s[m][j] * e^{+2pi i m t/1024}); scale pre-folded.
// ---------------------------------------------------------------------------
__global__ __launch_bounds__(256) void k_idft(const float* __restrict__ C2s,
                                              float* __restrict__ out) {
  const int bid = blockIdx.x;
  const int jh = bid & 1;
  const int tc = (bid >> 1) & 15;
  const int bh = bid >> 5;

  const int tid = threadIdx.x;
  const int lane = tid & 63;
  const int wv = __builtin_amdgcn_readfirstlane(tid >> 6);
  const int j0 = (jh * 4 + wv) * 8;
  const int t = tc * 64 + lane;

  const float* Cb = C2s + (size_t)bh * 8192 + (size_t)j0 * 2;  // + m*128

  // rotator: W(m) = e^{+2pi i m t/1024}, start m=0 -> (1,0)
  const float ph = (float)t * (1.0f / 512.0f);
  const float stc = cospif(ph), sts = sinpif(ph);
  float wr = 1.0f, wi = 0.0f;

  float acc[8] = {0.f};
#pragma unroll 4
  for (int m = 0; m < 64; ++m) {
    const float4* Cm = reinterpret_cast<const float4*>(Cb + (size_t)m * 128);
    const float4 b0 = Cm[0], b1 = Cm[1], b2 = Cm[2], b3 = Cm[3];
    acc[0] = fmaf(b0.x, wr, acc[0]); acc[0] = fmaf(-b0.y, wi, acc[0]);
    acc[1] = fmaf(b0.z, wr, acc[1]); acc[1] = fmaf(-b0.w, wi, acc[1]);
    acc[2] = fmaf(b1.x, wr, acc[2]); acc[2] = fmaf(-b1.y, wi, acc[2]);
    acc[3] = fmaf(b1.z, wr, acc[3]); acc[3] = fmaf(-b1.w, wi, acc[3]);
    acc[4] = fmaf(b2.x, wr, acc[4]); acc[4] = fmaf(-b2.y, wi, acc[4]);
    acc[5] = fmaf(b2.z, wr, acc[5]); acc[5] = fmaf(-b2.w, wi, acc[5]);
    acc[6] = fmaf(b3.x, wr, acc[6]); acc[6] = fmaf(-b3.y, wi, acc[6]);
    acc[7] = fmaf(b3.z, wr, acc[7]); acc[7] = fmaf(-b3.w, wi, acc[7]);
    const float nr = wr * stc - wi * sts;
    const float ni = wr * sts + wi * stc;
    wr = nr; wi = ni;
  }

  // out[bh][j][t], coalesced 256B per j
#pragma unroll
  for (int jj = 0; jj < 8; ++jj) {
    out[((size_t)bh * 64 + j0 + jj) * 1024 + t] = acc[jj];
  }
}

extern "C" void kernel_launch(void* const* d_in, const int* in_sizes, int n_in,
                              void* d_out, int out_size, void* d_ws, size_t ws_size,
                              hipStream_t stream) {
  const float* q   = (const float*)d_in[0];
  const float* k   = (const float*)d_in[1];
  // d_in[2] = value, unused by the reference forward
  const float* wre = (const float*)d_in[3];
  const float* wim = (const float*)d_in[4];
  float* out = (float*)d_out;
  float* ws  = (float*)d_ws;

  float* P   = ws;
  float* C1c = ws + C1C_OFF;
  float* C2s = ws + C2_OFF;
  float* T   = ws + T_OFF;

  k_twid <<<256,  256, 0, stream>>>(T);
  k_dft  <<<512,  256, 0, stream>>>(q, k, T, P);
  k_mid_a<<<256,  512, 0, stream>>>(P, C1c);
  k_mid_b<<<2048,  64, 0, stream>>>(C1c, wre, wim, C2s);
  k_idft <<<2048, 256, 0, stream>>>(C2s, out);
}

// Round 5
// 178.475 us; speedup vs baseline: 1.3673x; 1.3673x over previous
//
#include <hip/hip_runtime.h>
#include <hip/hip_bf16.h>
#include <cmath>

// Problem constants
#define BATCH 8
#define NH 8
#define BH 64          // BATCH*NH
#define SEQ 1024
#define DH 64          // head dim
#define NM 64          // modes

// ws layout (floats):
//  P   : [inp 2][tq 4][bh 64][c 2][m 64][d 64] = 4,194,304
//  C1c : [bh 64][i 64][q 64][c 2]              =   524,288
//  C2  : [bh 64][j 64][m 64][c 2]              =   524,288
#define P_PLANE 4096   // 64m*64d
#define P_FLOATS (2*4*64*2*4096)
#define C1C_OFF  P_FLOATS
#define C2_OFF   (C1C_OFF + 64*64*64*2)

// ---------------------------------------------------------------------------
// Kernel 1: partial forward DFT. grid = (bh 64, inp 2, tq 4) = 512 blocks
// x 256 thr (2 blocks/CU, 2 waves/SIMD -- grid-limited). Thread tile
// 4m x 8d x 2 t-streams (even/odd t): 2 ds_read_b128 feed 64 fma, halving
// the LDS port vs round 3 (24.6k cyc/CU) and doubling per-wave ILP.
// Even/odd partials combined with one shfl_xor(8) in the epilogue.
// Staging row stride 68 keeps all 32 banks live for the strided reads.
// ---------------------------------------------------------------------------
__global__ __launch_bounds__(256) void k_dft(const float* __restrict__ q,
                                             const float* __restrict__ k,
                                             float* __restrict__ P) {
  const int bid = blockIdx.x;
  const int bh = bid & 63;
  const int inp = (bid >> 6) & 1;
  const int tq = bid >> 7;  // 0..3, 256 samples each
  const float* x = (inp ? k : q) + (size_t)bh * (SEQ * DH);  // [t][d]

  __shared__ float xs[64 * 68];  // [t][d], row stride 68
  const int tid = threadIdx.x;
  const int dg = tid & 7;          // 8 d-groups of 8
  const int par = (tid >> 3) & 1;  // even/odd t stream
  const int mg = tid >> 4;         // 16 m-groups of 4
  const int m0 = mg * 4, d0 = dg * 8;

  float accr[4][8] = {{0.f}}, acci[4][8] = {{0.f}};

  // rotator step per mode: e^{-2*pi*i*m*2/1024} (t advances by 2)
  float stepc[4], steps[4];
#pragma unroll
  for (int mi = 0; mi < 4; ++mi) {
    float ph = (float)((m0 + mi) * 2) * (1.0f / 512.0f);
    stepc[mi] = cospif(ph);
    steps[mi] = -sinpif(ph);
  }

  for (int ch = 0; ch < 4; ++ch) {
    const int t0g = tq * 256 + ch * 64;
    // stage 64t x 64d chunk, LDS rows padded to 68
    const float4* src = reinterpret_cast<const float4*>(x + (size_t)t0g * DH);
#pragma unroll
    for (int i = 0; i < 4; ++i) {
      int idx = tid + i * 256;            // t*16 + d4
      int tt = idx >> 4, d4 = (idx & 15) * 4;
      *reinterpret_cast<float4*>(&xs[tt * 68 + d4]) = src[idx];
    }
    __syncthreads();

    // fresh twiddle at stream start: e^{-2*pi*i*m*(t0g+par)/1024}
    float wr[4], wi[4];
#pragma unroll
    for (int mi = 0; mi < 4; ++mi) {
      int p0 = ((m0 + mi) * (t0g + par)) & 1023;
      float ph = (float)p0 * (1.0f / 512.0f);
      wr[mi] = cospif(ph);
      wi[mi] = -sinpif(ph);
    }

#pragma unroll 4
    for (int tt = 0; tt < 32; ++tt) {
      const int t = tt * 2 + par;
      float4 a = *reinterpret_cast<const float4*>(&xs[t * 68 + d0]);
      float4 b = *reinterpret_cast<const float4*>(&xs[t * 68 + d0 + 4]);
      float xv[8] = {a.x, a.y, a.z, a.w, b.x, b.y, b.z, b.w};
#pragma unroll
      for (int mi = 0; mi < 4; ++mi) {
        float cwr = wr[mi], cwi = wi[mi];
#pragma unroll
        for (int di = 0; di < 8; ++di) {
          accr[mi][di] = fmaf(cwr, xv[di], accr[mi][di]);
          acci[mi][di] = fmaf(cwi, xv[di], acci[mi][di]);
        }
        float nr = cwr * stepc[mi] - cwi * steps[mi];
        float ni = cwr * steps[mi] + cwi * stepc[mi];
        wr[mi] = nr; wi[mi] = ni;
      }
    }
    __syncthreads();
  }

  // combine even/odd t-streams: partner lane differs in bit 3
#pragma unroll
  for (int mi = 0; mi < 4; ++mi) {
#pragma unroll
    for (int di = 0; di < 8; ++di) {
      accr[mi][di] += __shfl_xor(accr[mi][di], 8, 64);
      acci[mi][di] += __shfl_xor(acci[mi][di], 8, 64);
    }
  }

  if (par == 0) {
    // P[inp][tq][bh][c][m][d]
    const size_t base = (((size_t)inp * 4 + tq) * 64 + bh) * 2 * P_PLANE;
#pragma unroll
    for (int mi = 0; mi < 4; ++mi) {
      float* pr = P + base + (size_t)(m0 + mi) * 64 + d0;
      float* pi = P + base + P_PLANE + (size_t)(m0 + mi) * 64 + d0;
      *reinterpret_cast<float4*>(pr) =
          make_float4(accr[mi][0], accr[mi][1], accr[mi][2], accr[mi][3]);
      *reinterpret_cast<float4*>(pr + 4) =
          make_float4(accr[mi][4], accr[mi][5], accr[mi][6], accr[mi][7]);
      *reinterpret_cast<float4*>(pi) =
          make_float4(acci[mi][0], acci[mi][1], acci[mi][2], acci[mi][3]);
      *reinterpret_cast<float4*>(pi + 4) =
          make_float4(acci[mi][4], acci[mi][5], acci[mi][6], acci[mi][7]);
    }
  }
}

// stable complex tanh: tanh(x+iy) = (sinh2x + i sin2y)/(cosh2x + cos2y)
__device__ __forceinline__ void ctanh_f(float x, float y, float& rr, float& ri) {
  float a = 2.0f * x, b = 2.0f * y;
  if (fabsf(a) > 20.0f) {
    rr = (a > 0.0f) ? 1.0f : -1.0f;
    ri = 0.0f;
  } else {
    float ea = expf(a), ena = expf(-a);
    float sb, cb;
    sincosf(b, &sb, &cb);
    float den = 0.5f * (ea + ena) + cb;
    rr = 0.5f * (ea - ena) / den;
    ri = sb / den;
  }
}

// ---------------------------------------------------------------------------
// Kernel 2a: scores -> ctanh -> context -> C1. grid = (bh, q-eighth) = 512
// blocks x 256 thr. LDS 48 KB -> 3 blocks/CU = 12 waves/CU (round 3 had
// 256 blocks, 61 KB, 1 block/CU = 4 waves/CU -- latency-exposed).
// ---------------------------------------------------------------------------
__global__ __launch_bounds__(256) void k_mid_a(const float* __restrict__ P,
                                               float* __restrict__ C1c) {
  __shared__ float Kr[64][68], Ki[64][68];
  __shared__ float Qr[8][68], Qi[8][68];
  __shared__ float Ar[8][68], Ai[8][68];
  __shared__ float C1rs[64][9], C1is[64][9];

  const int tid = threadIdx.x;
  const int bh = blockIdx.x >> 3;
  const int qo = blockIdx.x & 7;  // 8 q's per block

  // P[inp][tq][bh][c][m][d]
  size_t pq[4], pk[4];
#pragma unroll
  for (int t = 0; t < 4; ++t) {
    pq[t] = (((size_t)(0 * 4 + t) * 64 + bh) * 2) * P_PLANE;
    pk[t] = (((size_t)(1 * 4 + t) * 64 + bh) * 2) * P_PLANE;
  }

  for (int idx = tid; idx < 4096; idx += 256) {
    int kk = idx >> 6, dd = idx & 63;
    float r = 0.f, im = 0.f;
#pragma unroll
    for (int t = 0; t < 4; ++t) {
      r += P[pk[t] + idx];
      im += P[pk[t] + P_PLANE + idx];
    }
    Kr[kk][dd] = r; Ki[kk][dd] = im;
  }
  for (int idx = tid; idx < 512; idx += 256) {
    int qi2 = idx >> 6, dd = idx & 63;
    int mm = qo * 8 + qi2;
    float r = 0.f, im = 0.f;
#pragma unroll
    for (int t = 0; t < 4; ++t) {
      r += P[pq[t] + mm * 64 + dd];
      im += P[pq[t] + P_PLANE + mm * 64 + dd];
    }
    Qr[qi2][dd] = r; Qi[qi2][dd] = im;
  }
  __syncthreads();

  // scores S[q][k] = sum_d Q[q][d]*K[k][d] (complex, no conj) -> ctanh
  {
    const int q = tid >> 5, k0 = tid & 31;
    float sr[2] = {0.f}, si[2] = {0.f};
    for (int d = 0; d < 64; d += 4) {
      const float4 qr = *reinterpret_cast<const float4*>(&Qr[q][d]);
      const float4 qi = *reinterpret_cast<const float4*>(&Qi[q][d]);
#pragma unroll
      for (int j = 0; j < 2; ++j) {
        const int kk = k0 + 32 * j;
        const float4 kr = *reinterpret_cast<const float4*>(&Kr[kk][d]);
        const float4 ki = *reinterpret_cast<const float4*>(&Ki[kk][d]);
        float s0 = sr[j], s1 = si[j];
        s0 = fmaf(qr.x, kr.x, s0); s0 = fmaf(-qi.x, ki.x, s0);
        s1 = fmaf(qr.x, ki.x, s1); s1 = fmaf(qi.x, kr.x, s1);
        s0 = fmaf(qr.y, kr.y, s0); s0 = fmaf(-qi.y, ki.y, s0);
        s1 = fmaf(qr.y, ki.y, s1); s1 = fmaf(qi.y, kr.y, s1);
        s0 = fmaf(qr.z, kr.z, s0); s0 = fmaf(-qi.z, ki.z, s0);
        s1 = fmaf(qr.z, ki.z, s1); s1 = fmaf(qi.z, kr.z, s1);
        s0 = fmaf(qr.w, kr.w, s0); s0 = fmaf(-qi.w, ki.w, s0);
        s1 = fmaf(qr.w, ki.w, s1); s1 = fmaf(qi.w, kr.w, s1);
        sr[j] = s0; si[j] = s1;
      }
    }
#pragma unroll
    for (int j = 0; j < 2; ++j) {
      float rr, ri;
      ctanh_f(sr[j], si[j], rr, ri);
      Ar[q][k0 + 32 * j] = rr;
      Ai[q][k0 + 32 * j] = ri;
    }
  }
  __syncthreads();

  // C1[d][q] = sum_k A[q][k]*K[k][d]
  {
    const int q = tid >> 5, d0 = (tid & 31) * 2;
    float cr[2] = {0.f}, ci[2] = {0.f};
    for (int kk = 0; kk < 64; ++kk) {
      float a_r = Ar[q][kk], a_i = Ai[q][kk];
      const float2 kr = *reinterpret_cast<const float2*>(&Kr[kk][d0]);
      const float2 ki = *reinterpret_cast<const float2*>(&Ki[kk][d0]);
      cr[0] = fmaf(a_r, kr.x, cr[0]); cr[0] = fmaf(-a_i, ki.x, cr[0]);
      ci[0] = fmaf(a_r, ki.x, ci[0]); ci[0] = fmaf(a_i, kr.x, ci[0]);
      cr[1] = fmaf(a_r, kr.y, cr[1]); cr[1] = fmaf(-a_i, ki.y, cr[1]);
      ci[1] = fmaf(a_r, ki.y, ci[1]); ci[1] = fmaf(a_i, kr.y, ci[1]);
    }
    C1rs[d0][q] = cr[0];     C1is[d0][q] = ci[0];
    C1rs[d0 + 1][q] = cr[1]; C1is[d0 + 1][q] = ci[1];
  }
  __syncthreads();

  // write C1c[bh][i][qglobal][2], interleaved complex
  for (int idx = tid; idx < 512; idx += 256) {
    int i = idx >> 3, ql = idx & 7;
    size_t o = (((size_t)bh * 64 + i) * 64 + qo * 8 + ql) * 2;
    *reinterpret_cast<float2*>(&C1c[o]) = make_float2(C1rs[i][ql], C1is[i][ql]);
  }
}

// ---------------------------------------------------------------------------
// Kernel 2b: C2[b,h,j,q] = sum_i C1[b,h,i,q] * (wre+i*wim)[h,i,j,q]
// lane = q -> w loads 256B coalesced; C1 float2 loads 512B coalesced.
// grid = (h 8, j 64, b-quarter 4) = 2048 one-wave blocks = 8 waves/CU.
// ---------------------------------------------------------------------------
__global__ __launch_bounds__(64) void k_mid_b(const float* __restrict__ C1c,
                                              const float* __restrict__ wre,
                                              const float* __restrict__ wim,
                                              float* __restrict__ C2) {
  const int bid = blockIdx.x;
  const int j = bid & 63;
  const int h = (bid >> 6) & 7;
  const int bq = bid >> 9;
  const int lane = threadIdx.x;  // q

  const int bh0 = (bq * 2 + 0) * 8 + h;
  const int bh1 = (bq * 2 + 1) * 8 + h;
  const float2* c1a = reinterpret_cast<const float2*>(C1c) + (size_t)bh0 * 4096 + lane;
  const float2* c1b = reinterpret_cast<const float2*>(C1c) + (size_t)bh1 * 4096 + lane;
  const float* wrp = wre + ((size_t)h * 4096 + j) * 64 + lane;
  const float* wip = wim + ((size_t)h * 4096 + j) * 64 + lane;

  float ar0 = 0.f, ai0 = 0.f, ar1 = 0.f, ai1 = 0.f;
#pragma unroll 8
  for (int i = 0; i < 64; ++i) {
    float wr = wrp[(size_t)i * 4096];
    float wi = wip[(size_t)i * 4096];
    float2 ca = c1a[(size_t)i * 64];
    float2 cb = c1b[(size_t)i * 64];
    ar0 = fmaf(ca.x, wr, ar0); ar0 = fmaf(-ca.y, wi, ar0);
    ai0 = fmaf(ca.x, wi, ai0); ai0 = fmaf(ca.y, wr, ai0);
    ar1 = fmaf(cb.x, wr, ar1); ar1 = fmaf(-cb.y, wi, ar1);
    ai1 = fmaf(cb.x, wi, ai1); ai1 = fmaf(cb.y, wr, ai1);
  }
  // C2[bh][j][m][2]
  *reinterpret_cast<float2*>(&C2[(((size_t)bh0 * 64 + j) * 64 + lane) * 2]) = make_float2(ar0, ai0);
  *reinterpret_cast<float2*>(&C2[(((size_t)bh1 * 64 + j) * 64 + lane) * 2]) = make_float2(ar1, ai1);
}

// ---------------------------------------------------------------------------
// Kernel 3: inverse partial DFT. grid = (bh, 8 t-chunks of 128) = 512 blocks
// = 8 waves/CU. Thread tile 4t x 8j: 16 LDS floats per m feed 64 fmaf.
// ---------------------------------------------------------------------------
__global__ __launch_bounds__(256) void k_idft(const float* __restrict__ C2,
                                              float* __restrict__ out) {
  __shared__ float Cr[64][68], Ci[64][68];
  const int tid = threadIdx.x;
  const int bh = blockIdx.x >> 3;
  const int tc = blockIdx.x & 7;
  const float s = 1.0f / (512.0f * 512.0f * 1024.0f);

  for (int idx = tid; idx < 4096; idx += 256) {
    int j = idx >> 6, m = idx & 63;
    float f = (m == 0) ? s : 2.0f * s;
    float2 c = *reinterpret_cast<const float2*>(&C2[(((size_t)bh * 64 + j) * 64 + m) * 2]);
    Cr[m][j] = f * c.x;
    Ci[m][j] = f * c.y;
  }
  __syncthreads();

  const int tg = tid & 31, jg = tid >> 5;
  const int t0 = tc * 128 + tg * 4, j0 = jg * 8;

  float sc[4], ss[4], wc[4], wsn[4];
#pragma unroll
  for (int kk = 0; kk < 4; ++kk) {
    float ph = (float)((t0 + kk) & 1023) * (1.0f / 512.0f);
    sc[kk] = cospif(ph);  // step e^{+2*pi*i*t/1024}
    ss[kk] = sinpif(ph);
    wc[kk] = 1.0f;        // m = 0
    wsn[kk] = 0.0f;
  }

  float acc[4][8] = {{0.f}};
  for (int m = 0; m < 64; ++m) {
    float4 c0 = *reinterpret_cast<const float4*>(&Cr[m][j0]);
    float4 c1 = *reinterpret_cast<const float4*>(&Cr[m][j0 + 4]);
    float4 e0 = *reinterpret_cast<const float4*>(&Ci[m][j0]);
    float4 e1 = *reinterpret_cast<const float4*>(&Ci[m][j0 + 4]);
    float crv[8] = {c0.x, c0.y, c0.z, c0.w, c1.x, c1.y, c1.z, c1.w};
    float civ[8] = {e0.x, e0.y, e0.z, e0.w, e1.x, e1.y, e1.z, e1.w};
#pragma unroll
    for (int kk = 0; kk < 4; ++kk) {
      float cw = wc[kk], sw = wsn[kk];
#pragma unroll
      for (int jj = 0; jj < 8; ++jj) {
        acc[kk][jj] = fmaf(crv[jj], cw, acc[kk][jj]);
        acc[kk][jj] = fmaf(-civ[jj], sw, acc[kk][jj]);
      }
      float nr = cw * sc[kk] - sw * ss[kk];
      float ni = cw * ss[kk] + sw * sc[kk];
      wc[kk] = nr; wsn[kk] = ni;
    }
  }

#pragma unroll
  for (int jj = 0; jj < 8; ++jj) {
    *reinterpret_cast<float4*>(&out[(size_t)bh * 65536 + (size_t)(j0 + jj) * 1024 + t0]) =
        make_float4(acc[0][jj], acc[1][jj], acc[2][jj], acc[3][jj]);
  }
}

extern "C" void kernel_launch(void* const* d_in, const int* in_sizes, int n_in,
                              void* d_out, int out_size, void* d_ws, size_t ws_size,
                              hipStream_t stream) {
  const float* q   = (const float*)d_in[0];
  const float* k   = (const float*)d_in[1];
  // d_in[2] = value, unused by the reference forward
  const float* wre = (const float*)d_in[3];
  const float* wim = (const float*)d_in[4];
  float* out = (float*)d_out;
  float* ws  = (float*)d_ws;

  float* P   = ws;
  float* C1c = ws + C1C_OFF;
  float* C2  = ws + C2_OFF;

  k_dft  <<<512,  256, 0, stream>>>(q, k, P);
  k_mid_a<<<512,  256, 0, stream>>>(P, C1c);
  k_mid_b<<<2048,  64, 0, stream>>>(C1c, wre, wim, C2);
  k_idft <<<512,  256, 0, stream>>>(C2, out);
}

// Round 6
// 166.615 us; speedup vs baseline: 1.4646x; 1.0712x over previous
//
#include <hip/hip_runtime.h>
#include <hip/hip_bf16.h>
#include <cmath>

// Problem constants
#define BATCH 8
#define NH 8
#define BH 64          // BATCH*NH
#define SEQ 1024
#define DH 64          // head dim
#define NM 64          // modes

// ws layout (floats):
//  P   : [inp 2][tq 8][bh 64][c 2][m 64][d 64] = 8,388,608  (fwd partials)
//  Pr  : [inp 2][bh 64][c 2][m 64][d 64]       = 1,048,576  (reduced)
//  C1c : [bh 64][i 64][q 64][c 2]              =   524,288
//  C2  : [bh 64][j 64][m 64][c 2]              =   524,288
// total 10,485,760 floats = 41.9 MB (ws is ~256 MB per round-5 fill size)
#define P_PLANE 4096   // 64m*64d
#define P_FLOATS (2*8*64*2*4096)
#define PR_OFF   P_FLOATS
#define C1C_OFF  (PR_OFF + 2*64*2*4096)
#define C2_OFF   (C1C_OFF + 64*64*64*2)

// ---------------------------------------------------------------------------
// Kernel 1: forward partial DFT with t<->t+512 symmetry (halves fma).
// X[m][d] = sum_{t'<512} (x[t'] + (-1)^m x[t'+512]) e^{-2pi i m t'/1024}
// grid = (bh 64, inp 2, tq 8) = 1024 blocks x 256 thr = 4 waves/SIMD.
// Thread: 4 modes (one parity) x 8 d, 2-way t-interleave (par streams),
// combined by shfl_xor(8). Staging forms se = a+b, so = a-b in LDS.
// ---------------------------------------------------------------------------
__global__ __launch_bounds__(256) void k_dft(const float* __restrict__ q,
                                             const float* __restrict__ k,
                                             float* __restrict__ P) {
  const int bid = blockIdx.x;
  const int bh = bid & 63;
  const int inp = (bid >> 6) & 1;
  const int tq = bid >> 7;  // 0..7, 64 t' each
  const float* x = (inp ? k : q) + (size_t)bh * (SEQ * DH);  // [t][d]

  __shared__ float se[64 * 68], so[64 * 68];  // row stride 68
  const int tid = threadIdx.x;
  const int dg = tid & 7;          // 8 d-groups of 8
  const int par = (tid >> 3) & 1;  // t-interleave stream
  const int pg = (tid >> 4) & 1;   // mode parity
  const int mg = tid >> 5;         // 0..7 -> 4 modes each
  const int d0 = dg * 8;
  // modes handled: m = 2*(mg*4+i) + pg, i in [0,4)

  const int t0g = tq * 64;
  {
    const float4* srcA = reinterpret_cast<const float4*>(x + (size_t)t0g * DH);
    const float4* srcB = reinterpret_cast<const float4*>(x + (size_t)(t0g + 512) * DH);
#pragma unroll
    for (int i = 0; i < 4; ++i) {
      int idx = tid + i * 256;  // t*16 + d4, 1024 float4 total
      int tt = idx >> 4, d4 = (idx & 15) * 4;
      float4 a = srcA[idx], b = srcB[idx];
      *reinterpret_cast<float4*>(&se[tt * 68 + d4]) =
          make_float4(a.x + b.x, a.y + b.y, a.z + b.z, a.w + b.w);
      *reinterpret_cast<float4*>(&so[tt * 68 + d4]) =
          make_float4(a.x - b.x, a.y - b.y, a.z - b.z, a.w - b.w);
    }
  }
  __syncthreads();

  const float* s = pg ? so : se;

  float accr[4][8] = {{0.f}}, acci[4][8] = {{0.f}};
  float stepc[4], steps[4], wr[4], wi[4];
#pragma unroll
  for (int mi = 0; mi < 4; ++mi) {
    const int m = 2 * (mg * 4 + mi) + pg;
    const int ps = (2 * m) & 1023;                 // t' advances by 2
    stepc[mi] = cospif((float)ps * (1.0f / 512.0f));
    steps[mi] = -sinpif((float)ps * (1.0f / 512.0f));
    const int p0 = (m * (t0g + par)) & 1023;
    wr[mi] = cospif((float)p0 * (1.0f / 512.0f));
    wi[mi] = -sinpif((float)p0 * (1.0f / 512.0f));
  }

#pragma unroll 4
  for (int k2 = 0; k2 < 32; ++k2) {
    const int tl = 2 * k2 + par;
    float4 a = *reinterpret_cast<const float4*>(&s[tl * 68 + d0]);
    float4 b = *reinterpret_cast<const float4*>(&s[tl * 68 + d0 + 4]);
    float xv[8] = {a.x, a.y, a.z, a.w, b.x, b.y, b.z, b.w};
#pragma unroll
    for (int mi = 0; mi < 4; ++mi) {
      float cwr = wr[mi], cwi = wi[mi];
#pragma unroll
      for (int di = 0; di < 8; ++di) {
        accr[mi][di] = fmaf(cwr, xv[di], accr[mi][di]);
        acci[mi][di] = fmaf(cwi, xv[di], acci[mi][di]);
      }
      float nr = cwr * stepc[mi] - cwi * steps[mi];
      float ni = cwr * steps[mi] + cwi * stepc[mi];
      wr[mi] = nr; wi[mi] = ni;
    }
  }

  // combine par streams (partner lane differs in bit 3)
#pragma unroll
  for (int mi = 0; mi < 4; ++mi) {
#pragma unroll
    for (int di = 0; di < 8; ++di) {
      accr[mi][di] += __shfl_xor(accr[mi][di], 8, 64);
      acci[mi][di] += __shfl_xor(acci[mi][di], 8, 64);
    }
  }

  if (par == 0) {
    // P[inp][tq][bh][c][m][d]
    const size_t base = (((size_t)inp * 8 + tq) * 64 + bh) * 2 * P_PLANE;
#pragma unroll
    for (int mi = 0; mi < 4; ++mi) {
      const int m = 2 * (mg * 4 + mi) + pg;
      float* pr = P + base + (size_t)m * 64 + d0;
      float* pi = P + base + P_PLANE + (size_t)m * 64 + d0;
      *reinterpret_cast<float4*>(pr) =
          make_float4(accr[mi][0], accr[mi][1], accr[mi][2], accr[mi][3]);
      *reinterpret_cast<float4*>(pr + 4) =
          make_float4(accr[mi][4], accr[mi][5], accr[mi][6], accr[mi][7]);
      *reinterpret_cast<float4*>(pi) =
          make_float4(acci[mi][0], acci[mi][1], acci[mi][2], acci[mi][3]);
      *reinterpret_cast<float4*>(pi + 4) =
          make_float4(acci[mi][4], acci[mi][5], acci[mi][6], acci[mi][7]);
    }
  }
}

// ---------------------------------------------------------------------------
// Kernel 1b: reduce 8 t-partials -> Pr[inp][bh][c][m][d]. 1024 x 256, float4.
// ---------------------------------------------------------------------------
__global__ __launch_bounds__(256) void k_red(const float* __restrict__ P,
                                             float* __restrict__ Pr) {
  const int idx = blockIdx.x * 256 + threadIdx.x;  // float4 idx, 262144 total
  const int inp = idx >> 17;                       // 131072 f4 per inp-plane
  const int r = idx & 131071;
  const float4* p4 = reinterpret_cast<const float4*>(P);
  const size_t base = ((size_t)inp * 8) * 131072 + r;
  float4 acc = p4[base];
#pragma unroll
  for (int t = 1; t < 8; ++t) {
    float4 v = p4[base + (size_t)t * 131072];
    acc.x += v.x; acc.y += v.y; acc.z += v.z; acc.w += v.w;
  }
  reinterpret_cast<float4*>(Pr)[idx] = acc;
}

// stable complex tanh: tanh(x+iy) = (sinh2x + i sin2y)/(cosh2x + cos2y)
__device__ __forceinline__ void ctanh_f(float x, float y, float& rr, float& ri) {
  float a = 2.0f * x, b = 2.0f * y;
  if (fabsf(a) > 20.0f) {
    rr = (a > 0.0f) ? 1.0f : -1.0f;
    ri = 0.0f;
  } else {
    float ea = expf(a), ena = expf(-a);
    float sb, cb;
    sincosf(b, &sb, &cb);
    float den = 0.5f * (ea + ena) + cb;
    rr = 0.5f * (ea - ena) / den;
    ri = sb / den;
  }
}

// ---------------------------------------------------------------------------
// Kernel 2a: scores -> ctanh -> context -> C1. grid = (bh, q-eighth) = 512
// blocks x 256 thr, 48 KB LDS -> 3 blocks/CU = 12 waves/CU. Stages from the
// reduced Pr plane (float4, no partial summation).
// ---------------------------------------------------------------------------
__global__ __launch_bounds__(256) void k_mid_a(const float* __restrict__ Pr,
                                               float* __restrict__ C1c) {
  __shared__ float Kr[64][68], Ki[64][68];
  __shared__ float Qr[8][68], Qi[8][68];
  __shared__ float Ar[8][68], Ai[8][68];
  __shared__ float C1rs[64][9], C1is[64][9];

  const int tid = threadIdx.x;
  const int bh = blockIdx.x >> 3;
  const int qo = blockIdx.x & 7;  // 8 q's per block

  // Pr[inp][bh][c][m][d]
  const float4* kbase = reinterpret_cast<const float4*>(Pr + ((size_t)(64 + bh)) * 8192);
  for (int idx = tid; idx < 1024; idx += 256) {
    int kk = idx >> 4, dd = (idx & 15) * 4;
    float4 vr = kbase[idx];
    float4 vi = kbase[idx + 1024];
    *reinterpret_cast<float4*>(&Kr[kk][dd]) = vr;
    *reinterpret_cast<float4*>(&Ki[kk][dd]) = vi;
  }
  {
    const float4* qbase =
        reinterpret_cast<const float4*>(Pr + (size_t)bh * 8192 + (size_t)qo * 8 * 64);
    if (tid < 128) {
      int qi2 = tid >> 4, dd = (tid & 15) * 4;
      float4 vr = qbase[tid];
      float4 vi = qbase[tid + 1024];  // +4096 floats = c=1 plane
      *reinterpret_cast<float4*>(&Qr[qi2][dd]) = vr;
      *reinterpret_cast<float4*>(&Qi[qi2][dd]) = vi;
    }
  }
  __syncthreads();

  // scores S[q][k] = sum_d Q[q][d]*K[k][d] (complex, no conj) -> ctanh
  {
    const int q = tid >> 5, k0 = tid & 31;
    float sr[2] = {0.f}, si[2] = {0.f};
    for (int d = 0; d < 64; d += 4) {
      const float4 qr = *reinterpret_cast<const float4*>(&Qr[q][d]);
      const float4 qi = *reinterpret_cast<const float4*>(&Qi[q][d]);
#pragma unroll
      for (int j = 0; j < 2; ++j) {
        const int kk = k0 + 32 * j;
        const float4 kr = *reinterpret_cast<const float4*>(&Kr[kk][d]);
        const float4 ki = *reinterpret_cast<const float4*>(&Ki[kk][d]);
        float s0 = sr[j], s1 = si[j];
        s0 = fmaf(qr.x, kr.x, s0); s0 = fmaf(-qi.x, ki.x, s0);
        s1 = fmaf(qr.x, ki.x, s1); s1 = fmaf(qi.x, kr.x, s1);
        s0 = fmaf(qr.y, kr.y, s0); s0 = fmaf(-qi.y, ki.y, s0);
        s1 = fmaf(qr.y, ki.y, s1); s1 = fmaf(qi.y, kr.y, s1);
        s0 = fmaf(qr.z, kr.z, s0); s0 = fmaf(-qi.z, ki.z, s0);
        s1 = fmaf(qr.z, ki.z, s1); s1 = fmaf(qi.z, kr.z, s1);
        s0 = fmaf(qr.w, kr.w, s0); s0 = fmaf(-qi.w, ki.w, s0);
        s1 = fmaf(qr.w, ki.w, s1); s1 = fmaf(qi.w, kr.w, s1);
        sr[j] = s0; si[j] = s1;
      }
    }
#pragma unroll
    for (int j = 0; j < 2; ++j) {
      float rr, ri;
      ctanh_f(sr[j], si[j], rr, ri);
      Ar[q][k0 + 32 * j] = rr;
      Ai[q][k0 + 32 * j] = ri;
    }
  }
  __syncthreads();

  // C1[d][q] = sum_k A[q][k]*K[k][d]
  {
    const int q = tid >> 5, d0 = (tid & 31) * 2;
    float cr[2] = {0.f}, ci[2] = {0.f};
    for (int kk = 0; kk < 64; ++kk) {
      float a_r = Ar[q][kk], a_i = Ai[q][kk];
      const float2 kr = *reinterpret_cast<const float2*>(&Kr[kk][d0]);
      const float2 ki = *reinterpret_cast<const float2*>(&Ki[kk][d0]);
      cr[0] = fmaf(a_r, kr.x, cr[0]); cr[0] = fmaf(-a_i, ki.x, cr[0]);
      ci[0] = fmaf(a_r, ki.x, ci[0]); ci[0] = fmaf(a_i, kr.x, ci[0]);
      cr[1] = fmaf(a_r, kr.y, cr[1]); cr[1] = fmaf(-a_i, ki.y, cr[1]);
      ci[1] = fmaf(a_r, ki.y, ci[1]); ci[1] = fmaf(a_i, kr.y, ci[1]);
    }
    C1rs[d0][q] = cr[0];     C1is[d0][q] = ci[0];
    C1rs[d0 + 1][q] = cr[1]; C1is[d0 + 1][q] = ci[1];
  }
  __syncthreads();

  // write C1c[bh][i][qglobal][2], interleaved complex
  for (int idx = tid; idx < 512; idx += 256) {
    int i = idx >> 3, ql = idx & 7;
    size_t o = (((size_t)bh * 64 + i) * 64 + qo * 8 + ql) * 2;
    *reinterpret_cast<float2*>(&C1c[o]) = make_float2(C1rs[i][ql], C1is[i][ql]);
  }
}

// ---------------------------------------------------------------------------
// Kernel 2b: C2[b,h,j,q] = sum_i C1[b,h,i,q] * (wre+i*wim)[h,i,j,q]
// lane = q -> coalesced. grid = (h 8, j 64, b-quarter 4) = 2048 one-wave
// blocks = 8 waves/CU.
// ---------------------------------------------------------------------------
__global__ __launch_bounds__(64) void k_mid_b(const float* __restrict__ C1c,
                                              const float* __restrict__ wre,
                                              const float* __restrict__ wim,
                                              float* __restrict__ C2) {
  const int bid = blockIdx.x;
  const int j = bid & 63;
  const int h = (bid >> 6) & 7;
  const int bq = bid >> 9;
  const int lane = threadIdx.x;  // q

  const int bh0 = (bq * 2 + 0) * 8 + h;
  const int bh1 = (bq * 2 + 1) * 8 + h;
  const float2* c1a = reinterpret_cast<const float2*>(C1c) + (size_t)bh0 * 4096 + lane;
  const float2* c1b = reinterpret_cast<const float2*>(C1c) + (size_t)bh1 * 4096 + lane;
  const float* wrp = wre + ((size_t)h * 4096 + j) * 64 + lane;
  const float* wip = wim + ((size_t)h * 4096 + j) * 64 + lane;

  float ar0 = 0.f, ai0 = 0.f, ar1 = 0.f, ai1 = 0.f;
#pragma unroll 8
  for (int i = 0; i < 64; ++i) {
    float wr = wrp[(size_t)i * 4096];
    float wi = wip[(size_t)i * 4096];
    float2 ca = c1a[(size_t)i * 64];
    float2 cb = c1b[(size_t)i * 64];
    ar0 = fmaf(ca.x, wr, ar0); ar0 = fmaf(-ca.y, wi, ar0);
    ai0 = fmaf(ca.x, wi, ai0); ai0 = fmaf(ca.y, wr, ai0);
    ar1 = fmaf(cb.x, wr, ar1); ar1 = fmaf(-cb.y, wi, ar1);
    ai1 = fmaf(cb.x, wi, ai1); ai1 = fmaf(cb.y, wr, ai1);
  }
  // C2[bh][j][m][2]
  *reinterpret_cast<float2*>(&C2[(((size_t)bh0 * 64 + j) * 64 + lane) * 2]) = make_float2(ar0, ai0);
  *reinterpret_cast<float2*>(&C2[(((size_t)bh1 * 64 + j) * 64 + lane) * 2]) = make_float2(ar1, ai1);
}

// ---------------------------------------------------------------------------
// Kernel 3: inverse partial DFT with the (-1)^m symmetry: each (t',j) cell
// produces out[t'] = E+O and out[t'+512] = E-O where E/O are even/odd-m
// partial sums (halves fma). grid = (bh 64, t'-chunk 8 of 64) = 512 blocks
// x 256 thr. Thread tile 2t' x 8j; scale pre-folded at staging.
// ---------------------------------------------------------------------------
__global__ __launch_bounds__(256) void k_idft(const float* __restrict__ C2,
                                              float* __restrict__ out) {
  __shared__ float Cr[64][68], Ci[64][68];
  const int tid = threadIdx.x;
  const int bh = blockIdx.x >> 3;
  const int tc = blockIdx.x & 7;
  const float s = 1.0f / (512.0f * 512.0f * 1024.0f);

  for (int idx = tid; idx < 4096; idx += 256) {
    int j = idx >> 6, m = idx & 63;
    float f = (m == 0) ? s : 2.0f * s;
    float2 c = *reinterpret_cast<const float2*>(&C2[(((size_t)bh * 64 + j) * 64 + m) * 2]);
    Cr[m][j] = f * c.x;
    Ci[m][j] = f * c.y;
  }
  __syncthreads();

  const int tg = tid & 31, jg = tid >> 5;
  const int tp0 = tc * 64 + tg * 2;  // t' base (2 consecutive t')
  const int j0 = jg * 8;

  float sc[2], ss[2], wc[2], wsn[2];
#pragma unroll
  for (int kk = 0; kk < 2; ++kk) {
    float ph = (float)((tp0 + kk) & 1023) * (1.0f / 512.0f);
    sc[kk] = cospif(ph);  // step e^{+2*pi*i*t'/1024} per m
    ss[kk] = sinpif(ph);
    wc[kk] = 1.0f;        // m = 0
    wsn[kk] = 0.0f;
  }

  float accE[2][8] = {{0.f}}, accO[2][8] = {{0.f}};
#pragma unroll 2
  for (int m = 0; m < 64; ++m) {
    float4 c0 = *reinterpret_cast<const float4*>(&Cr[m][j0]);
    float4 c1 = *reinterpret_cast<const float4*>(&Cr[m][j0 + 4]);
    float4 e0 = *reinterpret_cast<const float4*>(&Ci[m][j0]);
    float4 e1 = *reinterpret_cast<const float4*>(&Ci[m][j0 + 4]);
    float crv[8] = {c0.x, c0.y, c0.z, c0.w, c1.x, c1.y, c1.z, c1.w};
    float civ[8] = {e0.x, e0.y, e0.z, e0.w, e1.x, e1.y, e1.z, e1.w};
    float(*acc)[8] = (m & 1) ? accO : accE;
#pragma unroll
    for (int kk = 0; kk < 2; ++kk) {
      float cw = wc[kk], sw = wsn[kk];
#pragma unroll
      for (int jj = 0; jj < 8; ++jj) {
        acc[kk][jj] = fmaf(crv[jj], cw, acc[kk][jj]);
        acc[kk][jj] = fmaf(-civ[jj], sw, acc[kk][jj]);
      }
      float nr = cw * sc[kk] - sw * ss[kk];
      float ni = cw * ss[kk] + sw * sc[kk];
      wc[kk] = nr; wsn[kk] = ni;
    }
  }

  // out[bh][j][t]: (tp0, tp0+1) and (tp0+512, tp0+513), float2 each
#pragma unroll
  for (int jj = 0; jj < 8; ++jj) {
    float e0v = accE[0][jj], o0v = accO[0][jj];
    float e1v = accE[1][jj], o1v = accO[1][jj];
    float* row = &out[((size_t)bh * 64 + j0 + jj) * 1024];
    *reinterpret_cast<float2*>(&row[tp0])       = make_float2(e0v + o0v, e1v + o1v);
    *reinterpret_cast<float2*>(&row[tp0 + 512]) = make_float2(e0v - o0v, e1v - o1v);
  }
}

extern "C" void kernel_launch(void* const* d_in, const int* in_sizes, int n_in,
                              void* d_out, int out_size, void* d_ws, size_t ws_size,
                              hipStream_t stream) {
  const float* q   = (const float*)d_in[0];
  const float* k   = (const float*)d_in[1];
  // d_in[2] = value, unused by the reference forward
  const float* wre = (const float*)d_in[3];
  const float* wim = (const float*)d_in[4];
  float* out = (float*)d_out;
  float* ws  = (float*)d_ws;

  float* P   = ws;
  float* Pr  = ws + PR_OFF;
  float* C1c = ws + C1C_OFF;
  float* C2  = ws + C2_OFF;

  k_dft  <<<1024, 256, 0, stream>>>(q, k, P);
  k_red  <<<1024, 256, 0, stream>>>(P, Pr);
  k_mid_a<<<512,  256, 0, stream>>>(Pr, C1c);
  k_mid_b<<<2048,  64, 0, stream>>>(C1c, wre, wim, C2);
  k_idft <<<512,  256, 0, stream>>>(C2, out);
}